// Round 1
// baseline (110.520 us; speedup 1.0000x reference)
//
#include <hip/hip_runtime.h>

#define NBINS 30
// ws layout: [0,128): 32 x uint counts ; [128, 384): 32 x double ce-sums

__device__ __forceinline__ void ghm_process(float x0, float x1, int t,
                                            unsigned int* scnt, float* ssum) {
    // z = x_t - x_other ; nz = -z
    float z  = (t != 0) ? (x1 - x0) : (x0 - x1);
    float nz = -z;
    // stable: g = sigmoid(nz), ce = softplus(nz)
    float anz = fabsf(nz);
    float em  = __expf(-anz);          // exp(-|nz|) in (0,1]
    float ce  = fmaxf(nz, 0.0f) + __logf(1.0f + em);
    float sig = 1.0f / (1.0f + em);    // sigmoid(|nz|)
    float g   = (nz >= 0.0f) ? sig : (1.0f - sig);

    int bin = (int)(g * 30.0f);
    bin = bin < 0 ? 0 : (bin > NBINS - 1 ? NBINS - 1 : bin);

    atomicAdd(&scnt[bin], 1u);
    atomicAdd(&ssum[bin], ce);
}

__global__ __launch_bounds__(256) void ghm_pass1(const float4* __restrict__ x,
                                                 const int2* __restrict__ tgt,
                                                 unsigned int* __restrict__ gcnt,
                                                 double* __restrict__ gsum,
                                                 int npairs) {
    // per-wave replicated histograms: 4 waves x 32 bins (30 used, padded)
    __shared__ unsigned int scnt[4][32];
    __shared__ float        ssum[4][32];

    for (int i = threadIdx.x; i < 4 * 32; i += 256) {
        ((unsigned int*)scnt)[i] = 0u;
        ((float*)ssum)[i]        = 0.0f;
    }
    __syncthreads();

    const int wave = threadIdx.x >> 6;
    unsigned int* wcnt = scnt[wave];
    float*        wsum = ssum[wave];

    const int stride = gridDim.x * blockDim.x;
    for (int i = blockIdx.x * blockDim.x + threadIdx.x; i < npairs; i += stride) {
        float4 xv = x[i];     // two samples: (x0,x1) and (x2,x3)
        int2   tv = tgt[i];
        ghm_process(xv.x, xv.y, tv.x, wcnt, wsum);
        ghm_process(xv.z, xv.w, tv.y, wcnt, wsum);
    }
    __syncthreads();

    // reduce 4 wave histograms, one global atomic pair per bin per block
    if (threadIdx.x < NBINS) {
        int t = threadIdx.x;
        unsigned int c = scnt[0][t] + scnt[1][t] + scnt[2][t] + scnt[3][t];
        float        s = ssum[0][t] + ssum[1][t] + ssum[2][t] + ssum[3][t];
        if (c) atomicAdd(&gcnt[t], c);
        atomicAdd(&gsum[t], (double)s);
    }
}

__global__ void ghm_finalize(const unsigned int* __restrict__ gcnt,
                             const double* __restrict__ gsum,
                             float* __restrict__ out) {
    if (threadIdx.x == 0 && blockIdx.x == 0) {
        double acc = 0.0;
        int    n   = 0;
        for (int b = 0; b < NBINS; ++b) {
            unsigned int c = gcnt[b];
            if (c) { ++n; acc += gsum[b] / (double)c; }
        }
        double r = (n > 0) ? (4.0 * acc / (double)n) : 0.0;
        out[0] = (float)r;
    }
}

extern "C" void kernel_launch(void* const* d_in, const int* in_sizes, int n_in,
                              void* d_out, int out_size, void* d_ws, size_t ws_size,
                              hipStream_t stream) {
    const float4* x   = (const float4*)d_in[0];  // (B,2) f32 -> B/2 float4
    const int2*   tgt = (const int2*)d_in[1];    // (B,)  i32 -> B/2 int2
    const int B = in_sizes[1];
    const int npairs = B / 2;

    unsigned int* gcnt = (unsigned int*)d_ws;
    double*       gsum = (double*)((char*)d_ws + 128);

    hipMemsetAsync(d_ws, 0, 384, stream);

    ghm_pass1<<<2048, 256, 0, stream>>>(x, tgt, gcnt, gsum, npairs);
    ghm_finalize<<<1, 64, 0, stream>>>(gcnt, gsum, (float*)d_out);
}

// Round 2
// 57.537 us; speedup vs baseline: 1.9208x; 1.9208x over previous
//
#include <hip/hip_runtime.h>

#define NBINS 30
#define NREP  8
#define SCALE 65536.0f

// ws layout:
//   [0,    1024): NREP x 32 u32 counts
//   [1024, 3072): NREP x 32 u64 fixed-point ce sums (scale 2^16)

__device__ __forceinline__ void ghm_one(float x0, float x1, int t,
                                        unsigned int* wcnt, unsigned int* wsum) {
    // nz = -(x_t - x_other); g = sigmoid(nz); ce = softplus(nz)
    float nz  = (t != 0) ? (x0 - x1) : (x1 - x0);
    float anz = fabsf(nz);
    float em  = __expf(-anz);               // exp(-|nz|) in (0,1]
    float inv = 1.0f / (1.0f + em);
    float ce  = fmaxf(nz, 0.0f) + __logf(1.0f + em);
    float g   = (nz >= 0.0f) ? inv : (1.0f - inv);

    int bin = (int)(g * 30.0f);
    bin = bin < 0 ? 0 : (bin > NBINS - 1 ? NBINS - 1 : bin);

    unsigned int cf = (unsigned int)(ce * SCALE + 0.5f);  // fixed-point ce
    atomicAdd(&wcnt[bin], 1u);   // native ds_add_u32
    atomicAdd(&wsum[bin], cf);   // native ds_add_u32
}

__global__ __launch_bounds__(256) void ghm_pass1(const float4* __restrict__ x,
                                                 const int2* __restrict__ tgt,
                                                 unsigned int* __restrict__ gcnt,
                                                 unsigned long long* __restrict__ gsum,
                                                 int npairs) {
    // per-wave replicated histograms: 4 waves x 32 bins (30 used)
    __shared__ unsigned int scnt[4][32];
    __shared__ unsigned int ssum[4][32];

    if (threadIdx.x < 128) {
        ((unsigned int*)scnt)[threadIdx.x] = 0u;
        ((unsigned int*)ssum)[threadIdx.x] = 0u;
    }
    __syncthreads();

    const int wave = threadIdx.x >> 6;
    unsigned int* wcnt = scnt[wave];
    unsigned int* wsum = ssum[wave];

    const int stride = gridDim.x * blockDim.x;
    for (int i = blockIdx.x * blockDim.x + threadIdx.x; i < npairs; i += stride) {
        float4 xv = x[i];     // two samples: (x0,x1) and (x2,x3)
        int2   tv = tgt[i];
        ghm_one(xv.x, xv.y, tv.x, wcnt, wsum);
        ghm_one(xv.z, xv.w, tv.y, wcnt, wsum);
    }
    __syncthreads();

    // reduce 4 wave histograms; native integer global atomics, 8-way replicated
    if (threadIdx.x < NBINS) {
        int b = threadIdx.x;
        unsigned int c = scnt[0][b] + scnt[1][b] + scnt[2][b] + scnt[3][b];
        unsigned long long s = (unsigned long long)ssum[0][b] + ssum[1][b]
                             + ssum[2][b] + ssum[3][b];
        int rep = blockIdx.x & (NREP - 1);
        if (c) {
            atomicAdd(&gcnt[rep * 32 + b], c);
            atomicAdd(&gsum[rep * 32 + b], s);
        }
    }
}

__global__ void ghm_finalize(const unsigned int* __restrict__ gcnt,
                             const unsigned long long* __restrict__ gsum,
                             float* __restrict__ out) {
    if (threadIdx.x == 0 && blockIdx.x == 0) {
        double acc = 0.0;
        int    n   = 0;
        for (int b = 0; b < NBINS; ++b) {
            unsigned long long c = 0ull, s = 0ull;
            for (int r = 0; r < NREP; ++r) {
                c += gcnt[r * 32 + b];
                s += gsum[r * 32 + b];
            }
            if (c) { ++n; acc += ((double)s * (1.0 / 65536.0)) / (double)c; }
        }
        out[0] = (float)((n > 0) ? 4.0 * acc / (double)n : 0.0);
    }
}

extern "C" void kernel_launch(void* const* d_in, const int* in_sizes, int n_in,
                              void* d_out, int out_size, void* d_ws, size_t ws_size,
                              hipStream_t stream) {
    const float4* x   = (const float4*)d_in[0];  // (B,2) f32 -> B/2 float4
    const int2*   tgt = (const int2*)d_in[1];    // (B,)  i32 -> B/2 int2
    const int B = in_sizes[1];
    const int npairs = B / 2;

    unsigned int*       gcnt = (unsigned int*)d_ws;
    unsigned long long* gsum = (unsigned long long*)((char*)d_ws + 1024);

    hipMemsetAsync(d_ws, 0, 3072, stream);

    ghm_pass1<<<2048, 256, 0, stream>>>(x, tgt, gcnt, gsum, npairs);
    ghm_finalize<<<1, 64, 0, stream>>>(gcnt, gsum, (float*)d_out);
}